// Round 23
// baseline (107.217 us; speedup 1.0000x reference)
//
#include <hip/hip_runtime.h>

// StructuredElmanCell via 32x32 MFMA — barrier-free, TWO TILES PER WAVE.
// Evidence R17-R22: wall scales with wave-step count (R22), not instructions
// (R20 null) nor waves>4/SIMD (R21 null). So R23 halves wave-steps at
// constant tile-work: each wave owns the pc-pair {p0, p0+32} of one (b,h),
// two independent MFMA->silu chains per step (intra-step ILP covers the
// serial chain that co-resident waves couldn't). A-frag (B_proj rows) is
// SHARED by both tiles: loaded+packed once per step. 2048 waves = 512
// blocks; ~2 waves/SIMD at ~110-125 VGPR = same 4 tile-contexts as R22
// with half the rounds. GROUP=2 ring; alpha ping-pong; WARM=8 light warmup;
// paired-rcp silu; f16 RTZ frags (absmax 128 floor, validated).

namespace {
constexpr int T  = 1024;
constexpr int BS = 4;
constexpr int NH = 16;
constexpr int DS = 32;
constexpr int HD = 128;
constexpr int R  = 8;
constexpr int DI = NH * HD;                  // 2048
constexpr int GROUP = 2;

// element (float) strides per timestep
constexpr unsigned BF_T  = BS * NH * DS * R; // 16384
constexpr unsigned XF_T  = BS * NH * HD * R; // 65536
constexpr unsigned A_T   = BS * NH;          // 64
constexpr unsigned OUT_T = BS * DI;          // 8192 (z and out)

constexpr int SPAN   = 64;                   // emitted steps per slice
constexpr int WARM   = 8;                    // warmup steps (4 groups of 2)
constexpr int NSLICE = 16;

constexpr float LOG2E = 1.4426950408889634f;

typedef __attribute__((ext_vector_type(8)))  _Float16 half8;
typedef __attribute__((ext_vector_type(2)))  float    f32x2;
typedef __attribute__((ext_vector_type(16))) float    f32x16;
typedef __attribute__((ext_vector_type(4)))  unsigned u32x4;

__device__ __forceinline__ float fast_exp(float x) {
    return __builtin_amdgcn_exp2f(x * LOG2E);
}
__device__ __forceinline__ float fast_silu(float x) {
    return x * __builtin_amdgcn_rcpf(1.0f + __builtin_amdgcn_exp2f(x * -LOG2E));
}

// ---------------- pass 0: alpha = 1/(2+exp(ar+ab)) == sigmoid(-softplus) ---
__global__ __launch_bounds__(256)
void alpha_kernel(const float* __restrict__ ar_, const float* __restrict__ ab_,
                  float* __restrict__ alpha_) {
    int i = blockIdx.x * 256 + threadIdx.x;          // [T,BS,NH] flat
    float v = ar_[i] + ab_[i & (NH - 1)];
    alpha_[i] = __builtin_amdgcn_rcpf(2.0f + fast_exp(v));
}

// ---------------- pass 1: 32x32 MFMA scan, 2 tiles/wave --------------------
template<bool PRE>
__global__ __launch_bounds__(256, 2)
void elman32_kernel(const float* __restrict__ B_,
                    const float* __restrict__ X_,
                    const float* __restrict__ a_,   // PRE? alpha : alpha_raw
                    const float* __restrict__ ab_,
                    const float* __restrict__ z_,
                    const float* __restrict__ H0_,
                    float* __restrict__ out_,
                    float* __restrict__ Hf_)
{
    const int lane  = threadIdx.x & 63;
    const int W     = blockIdx.x * 4 + (threadIdx.x >> 6);  // 0..2047
    const int slice = W >> 7;            // 0..15
    const int Wl    = W & 127;
    const int pp    = Wl & 1;            // pc-pair: tiles {pp*64, pp*64+32}
    const int bh    = Wl >> 1;           // 0..63
    const int h     = bh & (NH - 1);
    const int b     = bh >> 4;
    const int l31   = lane & 31;
    const int khalf = lane >> 5;         // k-octet: 0 = real data, 1 = zero
    const int p0a   = pp * 64;
    const int p0b   = p0a + 32;

    const int t_begin   = slice * SPAN - (slice ? WARM : 0);
    const int ngroups   = (slice ? (SPAN + WARM) : SPAN) / GROUP;  // 36 / 32
    const int emit_from = slice ? (WARM / GROUP) : 0;              // 4 / 0

    const unsigned mz = khalf ? 0u : 0xFFFFFFFFu;   // A-frag octet-1 kill mask
    const float abv = PRE ? 0.0f : ab_[h];

    // C/D layout (m101, HW-verified): col = lane&31 (= p), row(i) =
    // (i&3) + 8*(i>>2) + 4*khalf (= n).
    f32x16 Ha, Hb;
    if (slice == 0) {
        #pragma unroll
        for (int i = 0; i < 16; ++i) {
            int row = (i & 3) + 8 * (i >> 2) + 4 * khalf;
            unsigned base = (unsigned)bh * 4096u + (unsigned)row * 128u;
            Ha[i] = H0_[base + (unsigned)(p0a + l31)];
            Hb[i] = H0_[base + (unsigned)(p0b + l31)];
        }
    } else {
        #pragma unroll
        for (int i = 0; i < 16; ++i) { Ha[i] = 0.0f; Hb[i] = 0.0f; }
    }

    // element offsets off SGPR bases, shifted to t_begin
    unsigned oB  = (unsigned)bh * (DS * R) + (unsigned)l31 * R
                 + (unsigned)t_begin * BF_T;              // shared A: B rows
    unsigned oXa = (unsigned)bh * (HD * R) + (unsigned)(p0a + l31) * R
                 + (unsigned)t_begin * XF_T;
    unsigned oXb = oXa + 32u * R;
    unsigned oA  = (unsigned)bh + (unsigned)(t_begin + (lane & 1)) * A_T;
    unsigned oZa = (unsigned)b * DI + (unsigned)h * HD + (unsigned)(p0a + l31)
                 + (unsigned)t_begin * OUT_T;
    unsigned oZb = oZa + 32u;
    unsigned oOa = oZa, oOb = oZb;

    u32x4 afr[GROUP], bfa[GROUP], bfb[GROUP];
    float zra[GROUP], zrb[GROUP];
    float av0, av1;                      // alpha ping-pong, 1 group ahead

    auto pk8 = [](const float4& v0, const float4& v1) -> u32x4 {
        u32x4 u;
        u.x = __builtin_bit_cast(unsigned, __builtin_amdgcn_cvt_pkrtz(v0.x, v0.y));
        u.y = __builtin_bit_cast(unsigned, __builtin_amdgcn_cvt_pkrtz(v0.z, v0.w));
        u.z = __builtin_bit_cast(unsigned, __builtin_amdgcn_cvt_pkrtz(v1.x, v1.y));
        u.w = __builtin_bit_cast(unsigned, __builtin_amdgcn_cvt_pkrtz(v1.z, v1.w));
        return u;
    };

    auto refill = [&](int s) {
        float4 b0  = *(const float4*)(B_ + oB  + (unsigned)s * BF_T);
        float4 b1  = *(const float4*)(B_ + oB  + (unsigned)s * BF_T + 4u);
        float4 xa0 = *(const float4*)(X_ + oXa + (unsigned)s * XF_T);
        float4 xa1 = *(const float4*)(X_ + oXa + (unsigned)s * XF_T + 4u);
        float4 xb0 = *(const float4*)(X_ + oXb + (unsigned)s * XF_T);
        float4 xb1 = *(const float4*)(X_ + oXb + (unsigned)s * XF_T + 4u);
        u32x4 a = pk8(b0, b1);
        a.x &= mz; a.y &= mz; a.z &= mz; a.w &= mz;   // khalf=1 -> zeros
        afr[s] = a;
        bfa[s] = pk8(xa0, xa1);
        bfb[s] = pk8(xb0, xb1);
        zra[s] = z_[oZa + (unsigned)s * OUT_T];
        zrb[s] = z_[oZb + (unsigned)s * OUT_T];
    };

    // prologue: ring <- group 0; alphas for groups 0 and 1
    #pragma unroll
    for (int s = 0; s < GROUP; ++s) refill(s);
    av0 = a_[oA];
    av1 = a_[oA + (unsigned)GROUP * A_T];
    oA += 2u * GROUP * A_T;              // next reload target: group 2
    oB += GROUP * BF_T; oXa += GROUP * XF_T; oXb += GROUP * XF_T;
    oZa += GROUP * OUT_T; oZb += GROUP * OUT_T;

    // silu over a 16-vector with paired reciprocals (16 exp + 8 rcp)
    auto silu16 = [](const f32x16& d, f32x16& Hdst) {
        f32x16 m = d * (-LOG2E);
        f32x16 e;
        #pragma unroll
        for (int i = 0; i < 16; ++i) e[i] = __builtin_amdgcn_exp2f(m[i]);
        f32x16 den = e + 1.0f;
        #pragma unroll
        for (int i = 0; i < 8; ++i) {
            float pd = den[2*i] * den[2*i+1];
            float q  = __builtin_amdgcn_rcpf(pd);
            Hdst[2*i]   = d[2*i]   * (den[2*i+1] * q);
            Hdst[2*i+1] = d[2*i+1] * (den[2*i]   * q);
        }
    };
    auto tree16 = [](const f32x16& H) -> float {
        f32x2 s0 = f32x2{H[0], H[1]}   + f32x2{H[2], H[3]};
        f32x2 s1 = f32x2{H[4], H[5]}   + f32x2{H[6], H[7]};
        f32x2 s2 = f32x2{H[8], H[9]}   + f32x2{H[10], H[11]};
        f32x2 s3 = f32x2{H[12], H[13]} + f32x2{H[14], H[15]};
        s0 += s1; s2 += s3; s0 += s2;
        return s0.x + s0.y;
    };

    auto step = [&](int s, bool emit, float av) {
        float ar = __int_as_float(
            __builtin_amdgcn_readlane(__float_as_int(av), s));
        float alpha = PRE ? ar
                          : __builtin_amdgcn_rcpf(2.0f + fast_exp(ar + abv));
        // two independent chains; shared A-frag
        f32x16 ca = Ha * alpha;
        f32x16 da = __builtin_amdgcn_mfma_f32_32x32x16_f16(
            __builtin_bit_cast(half8, afr[s]),
            __builtin_bit_cast(half8, bfa[s]), ca, 0, 0, 0);
        f32x16 cb = Hb * alpha;
        f32x16 db = __builtin_amdgcn_mfma_f32_32x32x16_f16(
            __builtin_bit_cast(half8, afr[s]),
            __builtin_bit_cast(half8, bfb[s]), cb, 0, 0, 0);
        silu16(da, Ha);
        silu16(db, Hb);
        if (emit) {
            float ypa = tree16(Ha);
            float ypb = tree16(Hb);
            float y2a = ypa + __shfl_xor(ypa, 32, 64);
            float y2b = ypb + __shfl_xor(ypb, 32, 64);
            float ga  = y2a * fast_silu(zra[s] + y2a);
            float gb  = y2b * fast_silu(zrb[s] + y2b);
            if (lane < 32) {
                out_[oOa + (unsigned)s * OUT_T] = ga;
                out_[oOb + (unsigned)s * OUT_T] = gb;
            }
        }
    };

    auto group_body = [&](bool emit, float av) {
        #pragma unroll
        for (int s = 0; s < GROUP; ++s) {
            step(s, emit, av);
            refill(s);                   // loads next group (offsets advanced)
        }
        oB += GROUP * BF_T; oXa += GROUP * XF_T; oXb += GROUP * XF_T;
        oZa += GROUP * OUT_T; oZb += GROUP * OUT_T;
        oOa += GROUP * OUT_T; oOb += GROUP * OUT_T;
    };

    // main: pairs of groups; reload av0/av1 one FULL group before use
    const int P = (ngroups - 2) / 2;     // 15 (slice 0) or 17
    int g = 0;
    #pragma unroll 1
    for (int gg = 0; gg < P; ++gg) {
        group_body(g >= emit_from, av0);
        av0 = a_[oA];                    // alpha for group g+2
        ++g;
        group_body(g >= emit_from, av1);
        av1 = a_[oA + (unsigned)GROUP * A_T];   // alpha for group g+2
        oA += 2u * GROUP * A_T;
        ++g;
    }
    // group ngroups-2 (even -> av0): steps + refill of the tail group
    group_body(true, av0);
    // group ngroups-1 (odd -> av1): tail, consume only
    #pragma unroll
    for (int s = 0; s < GROUP; ++s) step(s, true, av1);

    // H_final [BS,NH,DS,HD]: t=1023 lives in the last slice
    if (slice == NSLICE - 1) {
        #pragma unroll
        for (int i = 0; i < 16; ++i) {
            int row = (i & 3) + 8 * (i >> 2) + 4 * khalf;
            unsigned base = (unsigned)bh * 4096u + (unsigned)row * 128u;
            Hf_[base + (unsigned)(p0a + l31)] = Ha[i];
            Hf_[base + (unsigned)(p0b + l31)] = Hb[i];
        }
    }
}
} // namespace

extern "C" void kernel_launch(void* const* d_in, const int* in_sizes, int n_in,
                              void* d_out, int out_size, void* d_ws, size_t ws_size,
                              hipStream_t stream) {
    const float* B_proj     = (const float*)d_in[0];
    const float* X_proj     = (const float*)d_in[1];
    const float* alpha_raw  = (const float*)d_in[2];
    const float* alpha_bias = (const float*)d_in[3];
    const float* z          = (const float*)d_in[4];
    const float* H0         = (const float*)d_in[5];

    float* out = (float*)d_out;                       // [T,BS,DI] then Hf
    float* Hf  = out + (size_t)T * BS * DI;

    const size_t alpha_bytes = (size_t)T * BS * NH * sizeof(float);
    if (ws_size >= alpha_bytes) {
        float* aw = (float*)d_ws;
        alpha_kernel<<<T * BS * NH / 256, 256, 0, stream>>>(alpha_raw, alpha_bias, aw);
        elman32_kernel<true><<<512, 256, 0, stream>>>(
            B_proj, X_proj, aw, alpha_bias, z, H0, out, Hf);
    } else {
        elman32_kernel<false><<<512, 256, 0, stream>>>(
            B_proj, X_proj, alpha_raw, alpha_bias, z, H0, out, Hf);
    }
}

// Round 24
// 107.003 us; speedup vs baseline: 1.0020x; 1.0020x over previous
//
#include <hip/hip_runtime.h>

// StructuredElmanCell via 32x32 MFMA — barrier-free, load/pack split-pipeline.
// R17-R23 ledger: instr cuts null (R20), >4 waves unreachable (R21), steps
// prop. (R22), tiles/wave null (R23) => wall = tile-steps x ~890cy with
// per-wave duty only ~26%. Diagnosis: refill() packed (v_cvt_pkrtz) right
// after its loads -> at 60 VGPR the compiler can't sink the cvts past other
// stages' loads -> one exposed load->cvt memory latency (~1200cy) per step.
// R24: one-group software pipeline. P = packed frags for group g (consumed
// now); R = raw float4s for group g+1 (loaded one full group ago); each step
// issues loads for g+2. Load->pack distance = 2 steps >= HBM latency.
// Raw ring +32 VGPR -> ~110 under (256,2) -> 2 waves/SIMD; per-wave duty
// should rise ~3x, aggregate busy -> 75-90%.

namespace {
constexpr int T  = 1024;
constexpr int BS = 4;
constexpr int NH = 16;
constexpr int DS = 32;
constexpr int HD = 128;
constexpr int R  = 8;
constexpr int DI = NH * HD;                  // 2048
constexpr int GROUP = 2;

// element (float) strides per timestep
constexpr unsigned BF_T  = BS * NH * DS * R; // 16384
constexpr unsigned XF_T  = BS * NH * HD * R; // 65536
constexpr unsigned A_T   = BS * NH;          // 64
constexpr unsigned OUT_T = BS * DI;          // 8192 (z and out)

constexpr int SPAN   = 128;                  // emitted steps per slice
constexpr int WARM   = 8;                    // warmup steps (4 groups of 2)
constexpr int NSLICE = 8;

constexpr float LOG2E = 1.4426950408889634f;

typedef __attribute__((ext_vector_type(8)))  _Float16 half8;
typedef __attribute__((ext_vector_type(2)))  float    f32x2;
typedef __attribute__((ext_vector_type(16))) float    f32x16;
typedef __attribute__((ext_vector_type(4)))  unsigned u32x4;

__device__ __forceinline__ float fast_exp(float x) {
    return __builtin_amdgcn_exp2f(x * LOG2E);
}
__device__ __forceinline__ float fast_silu(float x) {
    return x * __builtin_amdgcn_rcpf(1.0f + __builtin_amdgcn_exp2f(x * -LOG2E));
}

// ---------------- pass 0: alpha = 1/(2+exp(ar+ab)) == sigmoid(-softplus) ---
__global__ __launch_bounds__(256)
void alpha_kernel(const float* __restrict__ ar_, const float* __restrict__ ab_,
                  float* __restrict__ alpha_) {
    int i = blockIdx.x * 256 + threadIdx.x;          // [T,BS,NH] flat
    float v = ar_[i] + ab_[i & (NH - 1)];
    alpha_[i] = __builtin_amdgcn_rcpf(2.0f + fast_exp(v));
}

// ---------------- pass 1: 32x32 MFMA scan, 8-way split, load/pack pipeline -
template<bool PRE>
__global__ __launch_bounds__(256, 2)
void elman32_kernel(const float* __restrict__ B_,
                    const float* __restrict__ X_,
                    const float* __restrict__ a_,   // PRE? alpha : alpha_raw
                    const float* __restrict__ ab_,
                    const float* __restrict__ z_,
                    const float* __restrict__ H0_,
                    float* __restrict__ out_,
                    float* __restrict__ Hf_)
{
    const int lane  = threadIdx.x & 63;
    const int W     = blockIdx.x * 4 + (threadIdx.x >> 6);  // 0..2047
    const int slice = W >> 8;            // 0..7
    const int Wl    = W & 255;
    const int pc    = Wl & 3;            // p-chunk of 32
    const int bh    = Wl >> 2;           // 0..63
    const int h     = bh & (NH - 1);
    const int b     = bh >> 4;
    const int l31   = lane & 31;
    const int khalf = lane >> 5;         // k-octet: 0 = real data, 1 = zero
    const int p0    = pc * 32;

    const int t_begin   = slice * SPAN - (slice ? WARM : 0);
    const int ngroups   = (slice ? (SPAN + WARM) : SPAN) / GROUP;  // 68 / 64
    const int emit_from = slice ? (WARM / GROUP) : 0;              // 4 / 0

    const unsigned mz = khalf ? 0u : 0xFFFFFFFFu;   // A-frag octet-1 kill mask
    const float abv = PRE ? 0.0f : ab_[h];

    // C/D layout (m101, HW-verified): col = lane&31 (= p), row(i) =
    // (i&3) + 8*(i>>2) + 4*khalf (= n).
    f32x16 H;
    if (slice == 0) {
        #pragma unroll
        for (int i = 0; i < 16; ++i) {
            int row = (i & 3) + 8 * (i >> 2) + 4 * khalf;
            H[i] = H0_[(unsigned)bh * 4096u + (unsigned)row * 128u
                       + (unsigned)(p0 + l31)];
        }
    } else {
        #pragma unroll
        for (int i = 0; i < 16; ++i) H[i] = 0.0f;   // contraction warmup
    }

    // element offsets off SGPR bases, shifted to t_begin.
    // oB/oX/oZ are the LOAD cursor (group being fetched); oO is the emit cursor.
    unsigned oB = (unsigned)bh * (DS * R) + (unsigned)l31 * R
                + (unsigned)t_begin * BF_T;               // A: B row n=l31
    unsigned oX = (unsigned)bh * (HD * R) + (unsigned)(p0 + l31) * R
                + (unsigned)t_begin * XF_T;               // B: X row p
    unsigned oA = (unsigned)bh + (unsigned)(t_begin + (lane & 1)) * A_T;
    unsigned oZ = (unsigned)b * DI + (unsigned)h * HD + (unsigned)(p0 + l31)
                + (unsigned)t_begin * OUT_T;
    unsigned oO = oZ;

    // packed set P (group g) and raw set R (group g+1)
    u32x4 afrP[GROUP], bfrP[GROUP];
    float zP[GROUP];
    float4 rB0[GROUP], rB1[GROUP], rX0[GROUP], rX1[GROUP];
    float  zR[GROUP];
    float av0, av1;                      // alpha ping-pong

    auto pk8 = [](const float4& v0, const float4& v1) -> u32x4 {
        u32x4 u;
        u.x = __builtin_bit_cast(unsigned, __builtin_amdgcn_cvt_pkrtz(v0.x, v0.y));
        u.y = __builtin_bit_cast(unsigned, __builtin_amdgcn_cvt_pkrtz(v0.z, v0.w));
        u.z = __builtin_bit_cast(unsigned, __builtin_amdgcn_cvt_pkrtz(v1.x, v1.y));
        u.w = __builtin_bit_cast(unsigned, __builtin_amdgcn_cvt_pkrtz(v1.z, v1.w));
        return u;
    };

    auto loadR = [&](int s) {            // raw loads at the LOAD cursor
        rB0[s] = *(const float4*)(B_ + oB + (unsigned)s * BF_T);
        rB1[s] = *(const float4*)(B_ + oB + (unsigned)s * BF_T + 4u);
        rX0[s] = *(const float4*)(X_ + oX + (unsigned)s * XF_T);
        rX1[s] = *(const float4*)(X_ + oX + (unsigned)s * XF_T + 4u);
        zR[s]  = z_[oZ + (unsigned)s * OUT_T];
    };
    auto packP = [&](int s) {            // R (loaded >=1 group ago) -> P
        u32x4 a = pk8(rB0[s], rB1[s]);
        a.x &= mz; a.y &= mz; a.z &= mz; a.w &= mz;
        afrP[s] = a;
        bfrP[s] = pk8(rX0[s], rX1[s]);
        zP[s]   = zR[s];
    };
    auto advance = [&]() {
        oB += GROUP * BF_T; oX += GROUP * XF_T; oZ += GROUP * OUT_T;
    };

    // prologue: raw g0 -> pack (one exposed wait, prologue only);
    // then raw g1 in flight; cursors end at g2.
    loadR(0); loadR(1);
    av0 = a_[oA];
    av1 = a_[oA + (unsigned)GROUP * A_T];
    oA += 2u * GROUP * A_T;
    packP(0); packP(1);
    advance();
    loadR(0); loadR(1);                  // group 1 raw, in flight
    advance();                           // load cursor now at group 2

    auto step = [&](int s, bool emit, float av) {
        float ar = __int_as_float(
            __builtin_amdgcn_readlane(__float_as_int(av), s));
        float alpha = PRE ? ar
                          : __builtin_amdgcn_rcpf(2.0f + fast_exp(ar + abv));
        f32x16 c = H * alpha;
        f32x16 d = __builtin_amdgcn_mfma_f32_32x32x16_f16(
            __builtin_bit_cast(half8, afrP[s]),
            __builtin_bit_cast(half8, bfrP[s]), c, 0, 0, 0);
        f32x16 m = d * (-LOG2E);
        f32x16 e;
        #pragma unroll
        for (int i = 0; i < 16; ++i) e[i] = __builtin_amdgcn_exp2f(m[i]);
        f32x16 den = e + 1.0f;
        #pragma unroll
        for (int i = 0; i < 8; ++i) {
            float pd = den[2*i] * den[2*i+1];
            float q  = __builtin_amdgcn_rcpf(pd);
            H[2*i]   = d[2*i]   * (den[2*i+1] * q);
            H[2*i+1] = d[2*i+1] * (den[2*i]   * q);
        }
        if (emit) {
            f32x2 s0 = f32x2{H[0], H[1]}   + f32x2{H[2], H[3]};
            f32x2 s1 = f32x2{H[4], H[5]}   + f32x2{H[6], H[7]};
            f32x2 s2 = f32x2{H[8], H[9]}   + f32x2{H[10], H[11]};
            f32x2 s3 = f32x2{H[12], H[13]} + f32x2{H[14], H[15]};
            s0 += s1; s2 += s3; s0 += s2;
            float yp = s0.x + s0.y;
            float y2 = yp + __shfl_xor(yp, 32, 64);
            float gt = y2 * fast_silu(zP[s] + y2);
            if (lane < 32) out_[oO + (unsigned)s * OUT_T] = gt;
        }
    };

    // full group body: consume P(g), repack P <- R(g+1), load R <- g+2
    auto group_body = [&](bool emit, float av) {
        #pragma unroll
        for (int s = 0; s < GROUP; ++s) {
            step(s, emit, av);
            packP(s);                    // raw loaded one full group ago
            loadR(s);                    // fetch group g+2 stage s
        }
        advance();
        oO += GROUP * OUT_T;
    };

    // main: groups 0..ngroups-3 (each loads g+2; last load -> ngroups-1)
    const int P2 = (ngroups - 2) / 2;    // 31 (slice 0) or 33
    int g = 0;
    #pragma unroll 1
    for (int gg = 0; gg < P2; ++gg) {
        group_body(g >= emit_from, av0);
        av0 = a_[oA];                    // alpha for group g+2
        ++g;
        group_body(g >= emit_from, av1);
        av1 = a_[oA + (unsigned)GROUP * A_T];   // alpha for group g+2
        oA += 2u * GROUP * A_T;
        ++g;
    }
    // group ngroups-2 (even -> av0): consume P, repack from R; no loads
    #pragma unroll
    for (int s = 0; s < GROUP; ++s) {
        step(s, true, av0);
        packP(s);
    }
    oO += GROUP * OUT_T;
    // group ngroups-1 (odd -> av1): consume only
    #pragma unroll
    for (int s = 0; s < GROUP; ++s) step(s, true, av1);

    // H_final [BS,NH,DS,HD]: t=1023 lives in the last slice
    if (slice == NSLICE - 1) {
        #pragma unroll
        for (int i = 0; i < 16; ++i) {
            int row = (i & 3) + 8 * (i >> 2) + 4 * khalf;
            Hf_[(unsigned)bh * 4096u + (unsigned)row * 128u
                + (unsigned)(p0 + l31)] = H[i];
        }
    }
}
} // namespace

extern "C" void kernel_launch(void* const* d_in, const int* in_sizes, int n_in,
                              void* d_out, int out_size, void* d_ws, size_t ws_size,
                              hipStream_t stream) {
    const float* B_proj     = (const float*)d_in[0];
    const float* X_proj     = (const float*)d_in[1];
    const float* alpha_raw  = (const float*)d_in[2];
    const float* alpha_bias = (const float*)d_in[3];
    const float* z          = (const float*)d_in[4];
    const float* H0         = (const float*)d_in[5];

    float* out = (float*)d_out;                       // [T,BS,DI] then Hf
    float* Hf  = out + (size_t)T * BS * DI;

    const size_t alpha_bytes = (size_t)T * BS * NH * sizeof(float);
    if (ws_size >= alpha_bytes) {
        float* aw = (float*)d_ws;
        alpha_kernel<<<T * BS * NH / 256, 256, 0, stream>>>(alpha_raw, alpha_bias, aw);
        elman32_kernel<true><<<512, 256, 0, stream>>>(
            B_proj, X_proj, aw, alpha_bias, z, H0, out, Hf);
    } else {
        elman32_kernel<false><<<512, 256, 0, stream>>>(
            B_proj, X_proj, alpha_raw, alpha_bias, z, H0, out, Hf);
    }
}

// Round 25
// 104.660 us; speedup vs baseline: 1.0244x; 1.0224x over previous
//
#include <hip/hip_runtime.h>

// StructuredElmanCell via 32x32 MFMA — barrier-free (R17-R24 structure).
// R25: Schraudolph exp2 for the 16 recurrence sigmoids. R22-R24 evidence:
// throughput invariant at ~890cy/tile-step across 2 or 4 waves/SIMD, 1-2
// tiles/wave, pipelined or not => SIMD is execution-saturated (VALUBusy ~50%
// undercounts; gfx94x derived-metric fallback). Largest exec block = 16
// v_exp_f32 (~16cy each). Replace with 2^u ~= bitcast(i32(u*2^23 +
// (127-0.0573)*2^23)): FMA+cvt per element (+-2.9% rel), hardware exp/rcp
// kept for the gate (direct output path) and alpha. Error budget: dSigma
// <=0.007 abs -> steady-state out-err ~15-150 on the 128 floor -> predicted
// absmax 150-330 < 473.6. Base kernel = R22 (GROUP=4, SPAN=64, WARM=8,
// 16 slices, grid 1024, alpha ping-pong, light warmup, paired-rcp).

namespace {
constexpr int T  = 1024;
constexpr int BS = 4;
constexpr int NH = 16;
constexpr int DS = 32;
constexpr int HD = 128;
constexpr int R  = 8;
constexpr int DI = NH * HD;                  // 2048
constexpr int GROUP = 4;

// element (float) strides per timestep
constexpr unsigned BF_T  = BS * NH * DS * R; // 16384
constexpr unsigned XF_T  = BS * NH * HD * R; // 65536
constexpr unsigned A_T   = BS * NH;          // 64
constexpr unsigned OUT_T = BS * DI;          // 8192 (z and out)

constexpr int SPAN   = 64;                   // emitted steps per slice
constexpr int WARM   = 8;                    // warmup steps (2 groups)
constexpr int NSLICE = 16;

constexpr float LOG2E = 1.4426950408889634f;
// Schraudolph: 2^u ~= bitcast(int(u*2^23 + B)), B = (127 - 0.05730496)*2^23
constexpr float SCHRA_A = 8388608.0f;        // 2^23
constexpr float SCHRA_B = 1064872508.0f;     // 1065353216 - 480708

typedef __attribute__((ext_vector_type(8)))  _Float16 half8;
typedef __attribute__((ext_vector_type(2)))  float    f32x2;
typedef __attribute__((ext_vector_type(16))) float    f32x16;
typedef __attribute__((ext_vector_type(4)))  unsigned u32x4;

__device__ __forceinline__ float fast_exp(float x) {
    return __builtin_amdgcn_exp2f(x * LOG2E);
}
__device__ __forceinline__ float fast_silu(float x) {
    return x * __builtin_amdgcn_rcpf(1.0f + __builtin_amdgcn_exp2f(x * -LOG2E));
}

// ---------------- pass 0: alpha = 1/(2+exp(ar+ab)) == sigmoid(-softplus) ---
__global__ __launch_bounds__(256)
void alpha_kernel(const float* __restrict__ ar_, const float* __restrict__ ab_,
                  float* __restrict__ alpha_) {
    int i = blockIdx.x * 256 + threadIdx.x;          // [T,BS,NH] flat
    float v = ar_[i] + ab_[i & (NH - 1)];
    alpha_[i] = __builtin_amdgcn_rcpf(2.0f + fast_exp(v));
}

// ---------------- pass 1: 32x32 MFMA scan, 16-way time-split ---------------
template<bool PRE>
__global__ __launch_bounds__(256, 2)
void elman32_kernel(const float* __restrict__ B_,
                    const float* __restrict__ X_,
                    const float* __restrict__ a_,   // PRE? alpha : alpha_raw
                    const float* __restrict__ ab_,
                    const float* __restrict__ z_,
                    const float* __restrict__ H0_,
                    float* __restrict__ out_,
                    float* __restrict__ Hf_)
{
    const int lane  = threadIdx.x & 63;
    const int W     = blockIdx.x * 4 + (threadIdx.x >> 6);  // 0..4095
    const int slice = W >> 8;            // 0..15
    const int Wl    = W & 255;
    const int pc    = Wl & 3;            // p-chunk of 32
    const int bh    = Wl >> 2;           // 0..63
    const int h     = bh & (NH - 1);
    const int b     = bh >> 4;
    const int l31   = lane & 31;
    const int khalf = lane >> 5;         // k-octet: 0 = real data, 1 = zero
    const int p0    = pc * 32;

    const int t_begin   = slice * SPAN - (slice ? WARM : 0);
    const int ngroups   = (slice ? (SPAN + WARM) : SPAN) / GROUP;  // 18 / 16
    const int emit_from = slice ? (WARM / GROUP) : 0;              // 2 / 0

    const unsigned mz = khalf ? 0u : 0xFFFFFFFFu;   // A-frag octet-1 kill mask
    const float abv = PRE ? 0.0f : ab_[h];

    // C/D layout (m101, HW-verified): col = lane&31 (= p), row(i) =
    // (i&3) + 8*(i>>2) + 4*khalf (= n).
    f32x16 H;
    if (slice == 0) {
        #pragma unroll
        for (int i = 0; i < 16; ++i) {
            int row = (i & 3) + 8 * (i >> 2) + 4 * khalf;
            H[i] = H0_[(unsigned)bh * 4096u + (unsigned)row * 128u
                       + (unsigned)(p0 + l31)];
        }
    } else {
        #pragma unroll
        for (int i = 0; i < 16; ++i) H[i] = 0.0f;   // contraction warmup
    }

    // element offsets off SGPR bases, shifted to t_begin
    unsigned oB = (unsigned)bh * (DS * R) + (unsigned)l31 * R
                + (unsigned)t_begin * BF_T;               // A: B row n=l31
    unsigned oX = (unsigned)bh * (HD * R) + (unsigned)(p0 + l31) * R
                + (unsigned)t_begin * XF_T;               // B: X row p
    unsigned oA = (unsigned)bh + (unsigned)(t_begin + (lane & 3)) * A_T;
    unsigned oZ = (unsigned)b * DI + (unsigned)h * HD + (unsigned)(p0 + l31)
                + (unsigned)t_begin * OUT_T;
    unsigned oO = oZ;

    u32x4 afr[GROUP], bfr[GROUP];
    float zr[GROUP];
    float av0, av1;                      // alpha ping-pong, 1 group ahead

    auto pk8 = [](const float4& v0, const float4& v1) -> u32x4 {
        u32x4 u;
        u.x = __builtin_bit_cast(unsigned, __builtin_amdgcn_cvt_pkrtz(v0.x, v0.y));
        u.y = __builtin_bit_cast(unsigned, __builtin_amdgcn_cvt_pkrtz(v0.z, v0.w));
        u.z = __builtin_bit_cast(unsigned, __builtin_amdgcn_cvt_pkrtz(v1.x, v1.y));
        u.w = __builtin_bit_cast(unsigned, __builtin_amdgcn_cvt_pkrtz(v1.z, v1.w));
        return u;
    };

    auto refill = [&](int s) {
        float4 b0 = *(const float4*)(B_ + oB + (unsigned)s * BF_T);
        float4 b1 = *(const float4*)(B_ + oB + (unsigned)s * BF_T + 4u);
        float4 x0 = *(const float4*)(X_ + oX + (unsigned)s * XF_T);
        float4 x1 = *(const float4*)(X_ + oX + (unsigned)s * XF_T + 4u);
        u32x4 a = pk8(b0, b1);
        a.x &= mz; a.y &= mz; a.z &= mz; a.w &= mz;   // khalf=1 -> zeros
        afr[s] = a;
        bfr[s] = pk8(x0, x1);                          // unmasked: A=0 kills it
        zr[s]  = z_[oZ + (unsigned)s * OUT_T];
    };

    // prologue: ring <- group 0; alphas for groups 0 and 1
    #pragma unroll
    for (int s = 0; s < GROUP; ++s) refill(s);
    av0 = a_[oA];
    av1 = a_[oA + (unsigned)GROUP * A_T];
    oA += 2u * GROUP * A_T;              // next reload target: group 2
    oB += GROUP * BF_T; oX += GROUP * XF_T; oZ += GROUP * OUT_T;

    auto step = [&](int s, bool emit, float av) {
        float ar = __int_as_float(
            __builtin_amdgcn_readlane(__float_as_int(av), s));
        float alpha = PRE ? ar
                          : __builtin_amdgcn_rcpf(2.0f + fast_exp(ar + abv));
        f32x16 c = H * alpha;
        f32x16 d = __builtin_amdgcn_mfma_f32_32x32x16_f16(
            __builtin_bit_cast(half8, afr[s]),
            __builtin_bit_cast(half8, bfr[s]), c, 0, 0, 0);
        // sigmoid denominator via Schraudolph 2^u (FMA + cvt, no v_exp)
        f32x16 m = d * (-LOG2E);
        f32x16 e;
        #pragma unroll
        for (int i = 0; i < 16; ++i) {
            float t = fmaf(m[i], SCHRA_A, SCHRA_B);
            e[i] = __uint_as_float((unsigned)(int)t);
        }
        f32x16 den = e + 1.0f;
        #pragma unroll
        for (int i = 0; i < 8; ++i) {
            float pd = den[2*i] * den[2*i+1];
            float q  = __builtin_amdgcn_rcpf(pd);
            H[2*i]   = d[2*i]   * (den[2*i+1] * q);
            H[2*i+1] = d[2*i+1] * (den[2*i]   * q);
        }
        if (emit) {     // light warmup: y-path only when emitting
            f32x2 s0 = f32x2{H[0], H[1]}   + f32x2{H[2], H[3]};
            f32x2 s1 = f32x2{H[4], H[5]}   + f32x2{H[6], H[7]};
            f32x2 s2 = f32x2{H[8], H[9]}   + f32x2{H[10], H[11]};
            f32x2 s3 = f32x2{H[12], H[13]} + f32x2{H[14], H[15]};
            s0 += s1; s2 += s3; s0 += s2;
            float yp = s0.x + s0.y;
            float y2 = yp + __shfl_xor(yp, 32, 64);
            float gt = y2 * fast_silu(zr[s] + y2);   // hardware exp in gate
            if (lane < 32) out_[oO + (unsigned)s * OUT_T] = gt;
        }
    };

    auto group_body = [&](bool emit, float av) {
        #pragma unroll
        for (int s = 0; s < GROUP; ++s) {
            step(s, emit, av);
            refill(s);                   // loads next group (offsets advanced)
        }
        oB += GROUP * BF_T; oX += GROUP * XF_T;
        oZ += GROUP * OUT_T; oO += GROUP * OUT_T;
    };

    // main: pairs of groups; reload av0/av1 one FULL group before use
    const int P = (ngroups - 2) / 2;     // 7 (slice 0) or 8
    int g = 0;
    #pragma unroll 1
    for (int gg = 0; gg < P; ++gg) {
        group_body(g >= emit_from, av0);
        av0 = a_[oA];                    // alpha for group g+2
        ++g;
        group_body(g >= emit_from, av1);
        av1 = a_[oA + (unsigned)GROUP * A_T];   // alpha for group g+2
        oA += 2u * GROUP * A_T;
        ++g;
    }
    // group ngroups-2 (even -> av0): steps + refill of the tail group
    group_body(true, av0);
    // group ngroups-1 (odd -> av1): tail, consume only
    #pragma unroll
    for (int s = 0; s < GROUP; ++s) step(s, true, av1);

    // H_final [BS,NH,DS,HD]: t=1023 lives in the last slice
    if (slice == NSLICE - 1) {
        #pragma unroll
        for (int i = 0; i < 16; ++i) {
            int row = (i & 3) + 8 * (i >> 2) + 4 * khalf;
            Hf_[(unsigned)bh * 4096u + (unsigned)row * 128u
                + (unsigned)(p0 + l31)] = H[i];
        }
    }
}
} // namespace

extern "C" void kernel_launch(void* const* d_in, const int* in_sizes, int n_in,
                              void* d_out, int out_size, void* d_ws, size_t ws_size,
                              hipStream_t stream) {
    const float* B_proj     = (const float*)d_in[0];
    const float* X_proj     = (const float*)d_in[1];
    const float* alpha_raw  = (const float*)d_in[2];
    const float* alpha_bias = (const float*)d_in[3];
    const float* z          = (const float*)d_in[4];
    const float* H0         = (const float*)d_in[5];

    float* out = (float*)d_out;                       // [T,BS,DI] then Hf
    float* Hf  = out + (size_t)T * BS * DI;

    const size_t alpha_bytes = (size_t)T * BS * NH * sizeof(float);
    if (ws_size >= alpha_bytes) {
        float* aw = (float*)d_ws;
        alpha_kernel<<<T * BS * NH / 256, 256, 0, stream>>>(alpha_raw, alpha_bias, aw);
        elman32_kernel<true><<<1024, 256, 0, stream>>>(
            B_proj, X_proj, aw, alpha_bias, z, H0, out, Hf);
    } else {
        elman32_kernel<false><<<1024, 256, 0, stream>>>(
            B_proj, X_proj, alpha_raw, alpha_bias, z, H0, out, Hf);
    }
}